// Round 1
// baseline (320.821 us; speedup 1.0000x reference)
//
#include <hip/hip_runtime.h>

// GNN_base: per (b,l): c = ids[b,l]; neighbors n_k = ids[b, l+d], d in {-8..-1, 1..8} (0 outside).
// e_k = edge_w[n_k==0 ? 0 : c*VOCAB+n_k]; Mn[f] = max_k e_k * emb[n_k][f] (emb row 0 is zero,
// so n_k==0 terms contribute exactly 0). y[b,f] = sum_l (1-nw_c)*Mn[f] + nw_c*emb[c][f].
//
// Structure: a chunk of CHUNK positions touches only CHUNK+16 distinct emb rows -> stage the
// window in LDS once. Each wave owns 4 consecutive positions; union window = 20 rows, each
// read once (ds_read_b128), applied via compile-time (j,q) conditions.
//
// Epilogue (CHANGED this round): NO d_ws usage at all. The harness re-poisons the workspace
// (two 1.024 GB fillBuffer dispatches @ ~152.6 us each) inside the timed window whenever the
// workspace is used -- that was ~305 us of the previous 320 us. Instead: tiny zero kernel on
// d_out (16 KB), then one hardware f32 atomicAdd per (b,f) per block (524K atomics over 4096
// addresses, <=128-way contention -> sub-us at the TCC; G12).

#define VOCAB 8000
#define FDIM  256
#define PNB   8
#define NK    16
#define BB    16
#define LL    2048
#define CHUNK 16              // l-positions per block
#define WIN   (CHUNK + 2*PNB) // 32 distinct emb rows per block
#define NCHUNK (LL / CHUNK)   // 128 blocks per batch row

// 16 blocks x 64 threads x 16 B = 16 KB = BB*FDIM floats. Fully overwrites d_out.
__global__ __launch_bounds__(64) void gnn_zero(float4* __restrict__ out)
{
    out[blockIdx.x * 64 + threadIdx.x] = make_float4(0.f, 0.f, 0.f, 0.f);
}

__global__ __launch_bounds__(256) void gnn_kernel(
    const int*   __restrict__ ids,      // B*L
    const float* __restrict__ emb,      // VOCAB*FDIM (row 0 == 0)
    const float* __restrict__ edge_w,   // VOCAB*VOCAB+1
    const float* __restrict__ node_w,   // VOCAB
    float*       __restrict__ out)      // [BB][FDIM], pre-zeroed; accumulated via atomics
{
    __shared__ float s_emb[WIN][FDIM];   // 32 KB staged embedding window
    __shared__ float s_ew [CHUNK][NK];   // 1 KB edge weights
    __shared__ int   s_tok[WIN];
    __shared__ float s_nw [CHUNK];
    __shared__ float s_red[4][FDIM];     // 4 KB cross-wave reduce

    const int b   = blockIdx.y;
    const int l0  = blockIdx.x * CHUNK;
    const int tid = threadIdx.x;
    const int* idrow = ids + b * LL;

    // ---- Phase A: window token ids (positions l0-8 .. l0+CHUNK+7) ----
    if (tid < WIN) {
        const int p = l0 - PNB + tid;
        int t = (p >= 0 && p < LL) ? idrow[p] : 0;
        t = (t < 0) ? 0 : ((t >= VOCAB) ? (VOCAB - 1) : t);   // safety clamp
        s_tok[tid] = t;
    }
    __syncthreads();

    // ---- Phase B: random edge-weight gathers (issue first: long latency).
    // Nontemporal: zero reuse — don't evict emb from L2/L3.
    {   // CHUNK*NK = 256 gathers, exactly one per thread
        const int ll = tid >> 4;
        const int k  = tid & (NK - 1);
        const int n  = s_tok[ll + k + (k >= PNB ? 1 : 0)];
        const int c  = s_tok[ll + PNB];
        const long long ei = (n == 0) ? 0LL : (long long)c * VOCAB + n;
        s_ew[ll][k] = __builtin_nontemporal_load(edge_w + ei);
        if (tid < CHUNK) s_nw[tid] = node_w[s_tok[tid + PNB]];
    }
    // ---- Phase B': stage WIN emb rows into LDS (coalesced float4) ----
    {   // WIN rows * 64 float4/row = 2048 float4 over 256 threads = 8 each
        #pragma unroll
        for (int j = 0; j < 8; ++j) {
            const int i    = tid + 256 * j;
            const int row  = i >> 6;
            const int col4 = (i & 63) << 2;
            const float4 v = *(const float4*)(emb + (size_t)s_tok[row] * FDIM + col4);
            *(float4*)&s_emb[row][col4] = v;
        }
    }
    __syncthreads();

    // ---- Phase C: wave w owns positions 4w..4w+3; union window = rows 4w..4w+19.
    const int wave = tid >> 6;
    const int lane = tid & 63;
    const int f0   = lane << 2;
    const int base = wave << 2;

    float4 m[4], rc[4];
    #pragma unroll
    for (int q = 0; q < 4; ++q)
        m[q] = make_float4(-INFINITY, -INFINITY, -INFINITY, -INFINITY);

    #pragma unroll
    for (int j = 0; j < 20; ++j) {
        const float4 r = *(const float4*)&s_emb[base + j][f0];  // ds_read_b128, once
        #pragma unroll
        for (int q = 0; q < 4; ++q) {
            const int d = j - q;                  // compile-time per (j,q)
            if (d < 0 || d > 16) continue;        // outside this position's window
            if (d == 8) { rc[q] = r; continue; }  // center row: capture for blend
            const int   k = (d < 8) ? d : d - 1;  // neighbor slot
            const float e = s_ew[base + q][k];    // LDS broadcast — conflict-free
            m[q].x = fmaxf(m[q].x, e * r.x);
            m[q].y = fmaxf(m[q].y, e * r.y);
            m[q].z = fmaxf(m[q].z, e * r.z);
            m[q].w = fmaxf(m[q].w, e * r.w);
        }
    }

    float4 acc = make_float4(0.f, 0.f, 0.f, 0.f);
    #pragma unroll
    for (int q = 0; q < 4; ++q) {
        const float nw = s_nw[base + q];
        const float w1 = 1.0f - nw;
        acc.x += w1 * m[q].x + nw * rc[q].x;
        acc.y += w1 * m[q].y + nw * rc[q].y;
        acc.z += w1 * m[q].z + nw * rc[q].z;
        acc.w += w1 * m[q].w + nw * rc[q].w;
    }

    // ---- Phase D: cross-wave reduce in LDS, then ONE hw f32 atomicAdd per (b,f) ----
    ((float4*)s_red[wave])[lane] = acc;
    __syncthreads();

    const float s = s_red[0][tid] + s_red[1][tid] + s_red[2][tid] + s_red[3][tid];
    // unsafeAtomicAdd -> global_atomic_add_f32 (no CAS loop). Values are normal-range,
    // denormal-flush semantics irrelevant. Device scope: correct across XCDs (G12/m20).
    unsafeAtomicAdd(out + b * FDIM + tid, s);
}

extern "C" void kernel_launch(void* const* d_in, const int* in_sizes, int n_in,
                              void* d_out, int out_size, void* d_ws, size_t ws_size,
                              hipStream_t stream) {
    // Select inputs by element count (all four distinct) — immune to ordering.
    const int*   ids    = nullptr;
    const float* emb    = nullptr;
    const float* edge_w = nullptr;
    const float* node_w = nullptr;
    for (int i = 0; i < n_in; ++i) {
        const long long sz = in_sizes[i];
        if      (sz == (long long)BB * LL)            ids    = (const int*)  d_in[i];
        else if (sz == (long long)VOCAB * FDIM)       emb    = (const float*)d_in[i];
        else if (sz == (long long)VOCAB * VOCAB + 1)  edge_w = (const float*)d_in[i];
        else if (sz == (long long)VOCAB)              node_w = (const float*)d_in[i];
    }
    float* out = (float*)d_out;
    (void)d_ws; (void)ws_size;   // deliberately untouched: avoid workspace re-poison cost

    gnn_zero<<<dim3(BB), 64, 0, stream>>>((float4*)out);
    dim3 grid(NCHUNK, BB);
    gnn_kernel<<<grid, 256, 0, stream>>>(ids, emb, edge_w, node_w, out);
}